// Round 7
// baseline (1157.143 us; speedup 1.0000x reference)
//
#include <hip/hip_runtime.h>
#include <stdint.h>

#define SEQ 128
#define BATCH 256
#define INPUT_BITS 256
#define STATE_BITS 256
#define N_IN 1024
#define N_ST 256
#define NB 16
#define RAM_WORDS 2048   // 2^16 bits / 32 bits per word
#define EX_SLOTS 4       // elastic exchange ring (up to 3 steps of cluster drift)

typedef unsigned long long u64;
typedef uint32_t u32x4 __attribute__((ext_vector_type(4)));

// Pack "bool as 32-bit word" -> bitmask. Each thread builds ONE output word
// from 32 consecutive source words.
__global__ __launch_bounds__(256)
void pack_bits_kernel(const u32x4* __restrict__ src, uint32_t* __restrict__ dst) {
    int i = blockIdx.x * blockDim.x + threadIdx.x;   // output word index
    const u32x4* p = src + (size_t)i * 8;
    uint32_t w = 0;
#pragma unroll
    for (int j = 0; j < 8; j++) {
        u32x4 v = __builtin_nontemporal_load(p + j);
        w |= (v.x != 0u ? 1u : 0u) << (4 * j + 0);
        w |= (v.y != 0u ? 1u : 0u) << (4 * j + 1);
        w |= (v.z != 0u ? 1u : 0u) << (4 * j + 2);
        w |= (v.w != 0u ? 1u : 0u) << (4 * j + 3);
    }
    dst[i] = w;
}

// Neuron-sliced automaton. Wave = one batch element; slice = blockIdx & 7
// (XCD round-robin) so each XCD's L2 caches its 1MB input-table slice + 2MB
// state tables. Cross-slice io exchange: tagged agent-scope relaxed atomics
// in a 4-slot ring (slot = t & 3). Safety: producer's publish@t+4 follows its
// gather@t+3, which required all slices' publish@t+3, each following that
// slice's gather@t+2, ... => all consumers of slot t%4 at step t are done
// before it is overwritten. Tags 1..128 never collide with 0xAAAA poison.
//
// KEY (round 7): gb = ((q+w)&31) | (((w+s)&7)<<5) — each wave of a block
// belongs to a DIFFERENT 8-block producer cluster (round 6 had all 8 waves
// in one cluster -> whole-CU phase-locked waits, VALUBusy 26%). Unique
// producer per (s,gb): w=((gb>>5)-s)&7, q=((gb&31)-w)&31.
__global__ __launch_bounds__(512)
void ram_sliced_kernel(
    const uint32_t* __restrict__ pseq,   // packed [SEQ][BATCH][8]
    const uint32_t* __restrict__ pinit,  // packed [BATCH][8]
    const int*      __restrict__ input_conn, // [N_IN][16]
    const int*      __restrict__ state_conn, // [N_ST][16]
    const uint32_t* __restrict__ pim,    // packed input tables [N_IN][2048]
    const uint32_t* __restrict__ psm,    // packed state tables [N_ST][2048]
    u64*            __restrict__ ex,     // exchange [EX_SLOTS][BATCH][32] u64
    int*            __restrict__ outs,   // [SEQ][BATCH][N_IN]
    int*            __restrict__ final_state) // [BATCH][N_ST]
{
    // per-wave context rows: [seq 8 | state 8 | io 32] words
    __shared__ uint32_t ctx[8 * 48];

    const int tid  = threadIdx.x;
    const int lane = tid & 63;
    const int w    = tid >> 6;          // wave id (0..7)
    const int s    = blockIdx.x & 7;    // neuron slice / XCD
    const int q    = blockIdx.x >> 3;   // 0..31
    const int gb   = ((q + w) & 31) | (((w + s) & 7) << 5);  // cluster-mixed
    const int base = w * 48;

    // Connection registers, packed as (ctx word index << 8) | bitpos.
    uint32_t icr[2][16];
#pragma unroll
    for (int m = 0; m < 2; m++) {
        int n = s * 128 + lane + 64 * m;
#pragma unroll
        for (int k = 0; k < 16; k++) {
            int c = input_conn[n * 16 + k];
            int sel = (c < 256) ? (c >> 5) : (8 + ((c - 256) >> 5));
            icr[m][k] = ((uint32_t)(base + sel) << 8) | (uint32_t)(c & 31);
        }
    }
    uint32_t scr[4][16];
#pragma unroll
    for (int m = 0; m < 4; m++) {
        int n = lane + 64 * m;
#pragma unroll
        for (int k = 0; k < 16; k++) {
            int c = state_conn[n * 16 + k];
            int sel = (c < 1024) ? (16 + (c >> 5)) : (8 + ((c - 1024) >> 5));
            scr[m][k] = ((uint32_t)(base + sel) << 8) | (uint32_t)(c & 31);
        }
    }

    // Initial state words + first seq-word prefetch (wave-internal LDS only).
    if (lane < 8) ctx[base + 8 + lane] = pinit[gb * 8 + lane];
    uint32_t sreg = 0;
    if (lane < 8) sreg = pseq[(size_t)gb * 8 + lane];  // t = 0

    uint32_t sb0 = 0, sb1 = 0, sb2 = 0, sb3 = 0;

    for (int t = 0; t < SEQ; t++) {
        const u64 tag = (u64)(t + 1);
        const size_t slot = ((size_t)(t & (EX_SLOTS - 1)) * BATCH + gb) * 32;

        if (lane < 8) ctx[base + lane] = sreg;                 // seq words for t
        if (t + 1 < SEQ && lane < 8)
            sreg = pseq[((size_t)(t + 1) * BATCH + gb) * 8 + lane];

        // ---- Phase 1: this slice's 128 input neurons for batch gb ----
        uint32_t bit0, bit1;
        int n0 = s * 128 + lane;
        {
            uint32_t a0 = 0, a1 = 0;
#pragma unroll
            for (int k = 0; k < 16; k++) {
                uint32_t r0 = icr[0][k], r1 = icr[1][k];
                a0 |= ((ctx[r0 >> 8] >> (r0 & 31)) & 1u) << k;
                a1 |= ((ctx[r1 >> 8] >> (r1 & 31)) & 1u) << k;
            }
            uint32_t t0 = pim[((size_t)n0 << 11) + (a0 >> 5)];
            uint32_t t1 = pim[((size_t)(n0 + 64) << 11) + (a1 >> 5)];
            bit0 = (t0 >> (a0 & 31)) & 1u;
            bit1 = (t1 >> (a1 & 31)) & 1u;
        }
        u64 m0 = __ballot(bit0 != 0u);
        u64 m1 = __ballot(bit1 != 0u);

        // Publish FIRST (producer latency off the critical path), then store outs.
        if (lane < 4) {
            uint32_t half = (lane < 2) ? (uint32_t)(m0 >> (lane * 32))
                                       : (uint32_t)(m1 >> ((lane - 2) * 32));
            u64 v = ((tag << 16) | (half & 0xFFFFu))
                  | ((((tag << 16) | (half >> 16))) << 32);
            __hip_atomic_store(&ex[slot + s * 4 + lane],
                               v, __ATOMIC_RELAXED, __HIP_MEMORY_SCOPE_AGENT);
        }
        {
            int* op = outs + ((size_t)t * BATCH + gb) * N_IN + n0;
            __builtin_nontemporal_store((int)bit0, op);
            __builtin_nontemporal_store((int)bit1, op + 64);
        }

        // ---- Gather all 1024 io bits for batch gb (spin on tags) ----
        if (lane < 32) {
            const u64* p = &ex[slot + lane];
            u64 v; int guard = 0;
            for (;;) {
                v = __hip_atomic_load(p, __ATOMIC_RELAXED, __HIP_MEMORY_SCOPE_AGENT);
                if ((((v >> 16) & 0xFFFFull) == tag) && ((v >> 48) == tag)) break;
                if (++guard > (1 << 22)) break;   // visible failure, no hang
                __builtin_amdgcn_s_sleep(1);
            }
            ctx[base + 16 + lane] =
                (uint32_t)(v & 0xFFFFu) | (((uint32_t)(v >> 32) & 0xFFFFu) << 16);
        }

        // ---- Phase 2: all 256 state neurons (replicated per slice) ----
        {
            uint32_t a0 = 0, a1 = 0, a2 = 0, a3 = 0;
#pragma unroll
            for (int k = 0; k < 16; k++) {
                uint32_t r0 = scr[0][k], r1 = scr[1][k], r2 = scr[2][k], r3 = scr[3][k];
                a0 |= ((ctx[r0 >> 8] >> (r0 & 31)) & 1u) << k;
                a1 |= ((ctx[r1 >> 8] >> (r1 & 31)) & 1u) << k;
                a2 |= ((ctx[r2 >> 8] >> (r2 & 31)) & 1u) << k;
                a3 |= ((ctx[r3 >> 8] >> (r3 & 31)) & 1u) << k;
            }
            uint32_t t0 = psm[((size_t)(lane      ) << 11) + (a0 >> 5)];
            uint32_t t1 = psm[((size_t)(lane +  64) << 11) + (a1 >> 5)];
            uint32_t t2 = psm[((size_t)(lane + 128) << 11) + (a2 >> 5)];
            uint32_t t3 = psm[((size_t)(lane + 192) << 11) + (a3 >> 5)];
            sb0 = (t0 >> (a0 & 31)) & 1u;
            sb1 = (t1 >> (a1 & 31)) & 1u;
            sb2 = (t2 >> (a2 & 31)) & 1u;
            sb3 = (t3 >> (a3 & 31)) & 1u;
        }
        u64 q0 = __ballot(sb0 != 0u);
        u64 q1 = __ballot(sb1 != 0u);
        u64 q2 = __ballot(sb2 != 0u);
        u64 q3 = __ballot(sb3 != 0u);
        if (lane < 8) {
            int mi = lane >> 1;
            u64 qq = (mi == 0) ? q0 : (mi == 1) ? q1 : (mi == 2) ? q2 : q3;
            ctx[base + 8 + lane] = (uint32_t)(qq >> ((lane & 1) * 32));
        }
    }

    if (s == ((0 - 0) & 7) && ((w + s) & 7) == (gb >> 5)) { /* s==0 path below */ }
    if (s == 0) {
        final_state[(size_t)gb * N_ST + lane +   0] = (int)sb0;
        final_state[(size_t)gb * N_ST + lane +  64] = (int)sb1;
        final_state[(size_t)gb * N_ST + lane + 128] = (int)sb2;
        final_state[(size_t)gb * N_ST + lane + 192] = (int)sb3;
    }
}

// ---------------- Fallback (ws too small): round-4 kernel, raw tables -------
__global__ __launch_bounds__(1024)
void ram_automaton_fallback(
    const uint32_t* __restrict__ seq_bits, const uint32_t* __restrict__ init_state,
    const int* __restrict__ input_conn, const int* __restrict__ state_conn,
    const uint32_t* __restrict__ im_raw, const uint32_t* __restrict__ sm_raw,
    int* __restrict__ outs, int* __restrict__ final_state)
{
    __shared__ uint32_t c0[16];
    __shared__ uint32_t c1[40];
    const int b = blockIdx.x, tid = threadIdx.x, lane = tid & 63;
    int ic[NB];
#pragma unroll
    for (int k = 0; k < NB; k++) ic[k] = input_conn[tid * NB + k];
    int sc[NB];
    if (tid < N_ST) {
#pragma unroll
        for (int k = 0; k < NB; k++) sc[k] = state_conn[tid * NB + k];
    }
    uint32_t nsbit = 0;
    if (tid < N_ST) nsbit = (init_state[(size_t)b * STATE_BITS + tid] != 0u) ? 1u : 0u;
    uint32_t inbit = 0;
    if (tid < INPUT_BITS) inbit = seq_bits[(size_t)b * INPUT_BITS + tid];
    for (int t = 0; t < SEQ; t++) {
        if (tid < INPUT_BITS) {
            u64 mi = __ballot(inbit != 0u);
            u64 ms = __ballot(nsbit != 0u);
            if ((lane & 31) == 0) {
                c0[tid >> 5] = (uint32_t)(mi >> (lane & 32));
                uint32_t wsd = (uint32_t)(ms >> (lane & 32));
                c0[8 + (tid >> 5)] = wsd; c1[32 + (tid >> 5)] = wsd;
            }
        }
        __syncthreads();
        if (t + 1 < SEQ && tid < INPUT_BITS)
            inbit = seq_bits[((size_t)(t + 1) * BATCH + b) * INPUT_BITS + tid];
        {
            int addr = 0;
#pragma unroll
            for (int k = 0; k < NB; k++) {
                int c = ic[k];
                addr |= (int)((c0[c >> 5] >> (c & 31)) & 1u) << k;
            }
            uint32_t bit = (im_raw[((size_t)tid << 16) + (size_t)addr] != 0u) ? 1u : 0u;
            __builtin_nontemporal_store((int)bit, outs + ((size_t)t * BATCH + b) * N_IN + tid);
            u64 m = __ballot(bit != 0u);
            if (lane == 0) { c1[tid >> 5] = (uint32_t)m; c1[(tid >> 5) + 1] = (uint32_t)(m >> 32); }
        }
        __syncthreads();
        if (tid < N_ST) {
            int addr = 0;
#pragma unroll
            for (int k = 0; k < NB; k++) {
                int c = sc[k];
                addr |= (int)((c1[c >> 5] >> (c & 31)) & 1u) << k;
            }
            nsbit = (sm_raw[((size_t)tid << 16) + (size_t)addr] != 0u) ? 1u : 0u;
        }
        __syncthreads();
    }
    if (tid < N_ST) final_state[(size_t)b * N_ST + tid] = (int)nsbit;
}

extern "C" void kernel_launch(void* const* d_in, const int* in_sizes, int n_in,
                              void* d_out, int out_size, void* d_ws, size_t ws_size,
                              hipStream_t stream) {
    const uint32_t* seq        = (const uint32_t*)d_in[0];
    const uint32_t* init_state = (const uint32_t*)d_in[1];
    const int*      input_conn = (const int*)d_in[2];
    const uint32_t* input_mem  = (const uint32_t*)d_in[3];
    const int*      state_conn = (const int*)d_in[4];
    const uint32_t* state_mem  = (const uint32_t*)d_in[5];

    int* outs = (int*)d_out;                       // [SEQ][BATCH][N_IN]
    int* fin  = outs + (size_t)SEQ * BATCH * N_IN; // [BATCH][N_ST]

    const size_t ex_u64    = (size_t)EX_SLOTS * BATCH * 32; // 32768 u64 = 256 KB
    const size_t pim_words = (size_t)N_IN * RAM_WORDS;      // 2,097,152
    const size_t psm_words = (size_t)N_ST * RAM_WORDS;      //   524,288
    const size_t pseq_words = (size_t)SEQ * BATCH * 8;      //   262,144
    const size_t pinit_words = (size_t)BATCH * 8;           //     2,048
    const size_t need = ex_u64 * 8 +
        (pim_words + psm_words + pseq_words + pinit_words) * 4;

    if (ws_size >= need) {
        u64*      ex    = (u64*)d_ws;
        uint32_t* pim   = (uint32_t*)(ex + ex_u64);
        uint32_t* psm   = pim + pim_words;
        uint32_t* pseq  = psm + psm_words;
        uint32_t* pinit = pseq + pseq_words;

        hipLaunchKernelGGL(pack_bits_kernel, dim3((unsigned)(pim_words / 256)),
                           dim3(256), 0, stream, (const u32x4*)input_mem, pim);
        hipLaunchKernelGGL(pack_bits_kernel, dim3((unsigned)(psm_words / 256)),
                           dim3(256), 0, stream, (const u32x4*)state_mem, psm);
        hipLaunchKernelGGL(pack_bits_kernel, dim3((unsigned)(pseq_words / 256)),
                           dim3(256), 0, stream, (const u32x4*)seq, pseq);
        hipLaunchKernelGGL(pack_bits_kernel, dim3((unsigned)(pinit_words / 256)),
                           dim3(256), 0, stream, (const u32x4*)init_state, pinit);

        hipLaunchKernelGGL(ram_sliced_kernel, dim3(BATCH), dim3(512), 0, stream,
                           pseq, pinit, input_conn, state_conn, pim, psm,
                           ex, outs, fin);
    } else {
        hipLaunchKernelGGL(ram_automaton_fallback, dim3(BATCH), dim3(1024), 0, stream,
                           seq, init_state, input_conn, state_conn,
                           input_mem, state_mem, outs, fin);
    }
}

// Round 8
// 1135.788 us; speedup vs baseline: 1.0188x; 1.0188x over previous
//
#include <hip/hip_runtime.h>
#include <stdint.h>

#define SEQ 128
#define BATCH 256
#define INPUT_BITS 256
#define STATE_BITS 256
#define N_IN 1024
#define N_ST 256
#define NB 16
#define RAM_WORDS 2048   // 2^16 bits / 32 bits per word
#define EX_SLOTS 4       // elastic exchange ring

typedef unsigned long long u64;
typedef uint32_t u32x4 __attribute__((ext_vector_type(4)));

__global__ __launch_bounds__(256)
void pack_bits_kernel(const u32x4* __restrict__ src, uint32_t* __restrict__ dst) {
    int i = blockIdx.x * blockDim.x + threadIdx.x;   // output word index
    const u32x4* p = src + (size_t)i * 8;
    uint32_t w = 0;
#pragma unroll
    for (int j = 0; j < 8; j++) {
        u32x4 v = __builtin_nontemporal_load(p + j);
        w |= (v.x != 0u ? 1u : 0u) << (4 * j + 0);
        w |= (v.y != 0u ? 1u : 0u) << (4 * j + 1);
        w |= (v.z != 0u ? 1u : 0u) << (4 * j + 2);
        w |= (v.w != 0u ? 1u : 0u) << (4 * j + 3);
    }
    dst[i] = w;
}

// Round 8: 4 slices (256 input neurons each), 256-thread blocks (4 waves,
// 1 wave/SIMD — no SIMD sharing on the serial chain). slice = blockIdx & 3;
// blocks of slice s land on XCDs {s, s+4} (blockIdx%8 round-robin), so each
// XCD caches one 2MB pim slice + 2MB psm. Chain = 4 waves (one per slice)
// for one batch element; exchange via tagged agent-scope relaxed atomics in
// a 4-slot ring. gb mixing has a w*s cross-term so peer blocks depend on the
// wave index (round 7's mixing collapsed to closed 4-block clusters).
// Self-skip: a wave fills its own 8 io words from registers and polls only
// the 24 remote words; the first poll overlaps the outs stores.
__global__ __launch_bounds__(256)
void ram_sliced4_kernel(
    const uint32_t* __restrict__ pseq,   // packed [SEQ][BATCH][8]
    const uint32_t* __restrict__ pinit,  // packed [BATCH][8]
    const int*      __restrict__ input_conn, // [N_IN][16]
    const int*      __restrict__ state_conn, // [N_ST][16]
    const uint32_t* __restrict__ pim,    // packed input tables [N_IN][2048]
    const uint32_t* __restrict__ psm,    // packed state tables [N_ST][2048]
    u64*            __restrict__ ex,     // exchange [EX_SLOTS][BATCH][32] u64
    int*            __restrict__ outs,   // [SEQ][BATCH][N_IN]
    int*            __restrict__ final_state) // [BATCH][N_ST]
{
    // per-wave context rows: [seq 8 | state 8 | io 32] words
    __shared__ uint32_t ctx[4 * 48];

    const int tid  = threadIdx.x;
    const int lane = tid & 63;
    const int w    = tid >> 6;          // wave id (0..3)
    const int s    = blockIdx.x & 3;    // slice
    const int q    = blockIdx.x >> 2;   // 0..63
    // unique per (s,gb): w = gb>>6; q = ((gb&63) - 17w - 13s - 5ws) & 63.
    const int gb   = ((q + 17 * w + 13 * s + 5 * w * s) & 63) | (w << 6);
    const int base = w * 48;

    // Connection registers, packed as (ctx word index << 8) | bitpos.
    uint32_t icr[4][16];
#pragma unroll
    for (int m = 0; m < 4; m++) {
        int n = s * 256 + lane + 64 * m;
#pragma unroll
        for (int k = 0; k < 16; k++) {
            int c = input_conn[n * 16 + k];
            int sel = (c < 256) ? (c >> 5) : (8 + ((c - 256) >> 5));
            icr[m][k] = ((uint32_t)(base + sel) << 8) | (uint32_t)(c & 31);
        }
    }
    uint32_t scr[4][16];
#pragma unroll
    for (int m = 0; m < 4; m++) {
        int n = lane + 64 * m;
#pragma unroll
        for (int k = 0; k < 16; k++) {
            int c = state_conn[n * 16 + k];
            int sel = (c < 1024) ? (16 + (c >> 5)) : (8 + ((c - 1024) >> 5));
            scr[m][k] = ((uint32_t)(base + sel) << 8) | (uint32_t)(c & 31);
        }
    }

    if (lane < 8) ctx[base + 8 + lane] = pinit[gb * 8 + lane];
    uint32_t sreg = 0;
    if (lane < 8) sreg = pseq[(size_t)gb * 8 + lane];  // t = 0

    uint32_t sb0 = 0, sb1 = 0, sb2 = 0, sb3 = 0;

    for (int t = 0; t < SEQ; t++) {
        const u64 tag = (u64)(t + 1);
        const size_t slot = ((size_t)(t & (EX_SLOTS - 1)) * BATCH + gb) * 32;

        if (lane < 8) ctx[base + lane] = sreg;                 // seq words for t
        if (t + 1 < SEQ && lane < 8)
            sreg = pseq[((size_t)(t + 1) * BATCH + gb) * 8 + lane];

        // ---- Phase 1: this slice's 256 input neurons for batch gb ----
        uint32_t b0, b1, b2, b3;
        {
            uint32_t a0 = 0, a1 = 0, a2 = 0, a3 = 0;
#pragma unroll
            for (int k = 0; k < 16; k++) {
                uint32_t r0 = icr[0][k], r1 = icr[1][k], r2 = icr[2][k], r3 = icr[3][k];
                a0 |= ((ctx[r0 >> 8] >> (r0 & 31)) & 1u) << k;
                a1 |= ((ctx[r1 >> 8] >> (r1 & 31)) & 1u) << k;
                a2 |= ((ctx[r2 >> 8] >> (r2 & 31)) & 1u) << k;
                a3 |= ((ctx[r3 >> 8] >> (r3 & 31)) & 1u) << k;
            }
            int n0 = s * 256 + lane;
            uint32_t t0 = pim[((size_t)n0 << 11) + (a0 >> 5)];
            uint32_t t1 = pim[((size_t)(n0 +  64) << 11) + (a1 >> 5)];
            uint32_t t2 = pim[((size_t)(n0 + 128) << 11) + (a2 >> 5)];
            uint32_t t3 = pim[((size_t)(n0 + 192) << 11) + (a3 >> 5)];
            b0 = (t0 >> (a0 & 31)) & 1u;
            b1 = (t1 >> (a1 & 31)) & 1u;
            b2 = (t2 >> (a2 & 31)) & 1u;
            b3 = (t3 >> (a3 & 31)) & 1u;
        }
        u64 mball0 = __ballot(b0 != 0u);
        u64 mball1 = __ballot(b1 != 0u);
        u64 mball2 = __ballot(b2 != 0u);
        u64 mball3 = __ballot(b3 != 0u);

        // Publish immediately: 8 u64, word i = io dwords (2i,2i+1) of this slice.
        if (lane < 8) {
            u64 mm = (lane < 4) ? ((lane < 2) ? mball0 : mball1)
                                : ((lane < 6) ? mball2 : mball3);
            uint32_t lo32 = (uint32_t)(mm >> ((lane & 1) * 32));
            u64 v = ((tag << 16) | (lo32 & 0xFFFFu))
                  | ((((tag << 16) | (lo32 >> 16))) << 32);
            __hip_atomic_store(&ex[slot + s * 8 + lane],
                               v, __ATOMIC_RELAXED, __HIP_MEMORY_SCOPE_AGENT);
        }

        // Early first poll of remote words (overlaps the outs stores below).
        const bool gatherer = (lane < 32);
        const bool own      = gatherer && ((lane >> 3) == s);
        const u64* pp = &ex[slot + lane];
        u64 v = 0;
        if (gatherer && !own)
            v = __hip_atomic_load(pp, __ATOMIC_RELAXED, __HIP_MEMORY_SCOPE_AGENT);

        // Output stores (off critical path).
        {
            int* op = outs + ((size_t)t * BATCH + gb) * N_IN + s * 256 + lane;
            __builtin_nontemporal_store((int)b0, op);
            __builtin_nontemporal_store((int)b1, op + 64);
            __builtin_nontemporal_store((int)b2, op + 128);
            __builtin_nontemporal_store((int)b3, op + 192);
        }

        // ---- Gather all 1024 io bits ----
        if (gatherer) {
            if (own) {
                int i = lane & 7;
                u64 mm = (i < 4) ? ((i < 2) ? mball0 : mball1)
                                 : ((i < 6) ? mball2 : mball3);
                ctx[base + 16 + lane] = (uint32_t)(mm >> ((i & 1) * 32));
            } else {
                int guard = 0;
                while ((((v >> 16) & 0xFFFFull) != tag) || ((v >> 48) != tag)) {
                    if (++guard > (1 << 22)) break;   // visible failure, no hang
                    __builtin_amdgcn_s_sleep(1);
                    v = __hip_atomic_load(pp, __ATOMIC_RELAXED, __HIP_MEMORY_SCOPE_AGENT);
                }
                ctx[base + 16 + lane] =
                    (uint32_t)(v & 0xFFFFu) | (((uint32_t)(v >> 32) & 0xFFFFu) << 16);
            }
        }

        // ---- Phase 2: all 256 state neurons (replicated per slice) ----
        {
            uint32_t a0 = 0, a1 = 0, a2 = 0, a3 = 0;
#pragma unroll
            for (int k = 0; k < 16; k++) {
                uint32_t r0 = scr[0][k], r1 = scr[1][k], r2 = scr[2][k], r3 = scr[3][k];
                a0 |= ((ctx[r0 >> 8] >> (r0 & 31)) & 1u) << k;
                a1 |= ((ctx[r1 >> 8] >> (r1 & 31)) & 1u) << k;
                a2 |= ((ctx[r2 >> 8] >> (r2 & 31)) & 1u) << k;
                a3 |= ((ctx[r3 >> 8] >> (r3 & 31)) & 1u) << k;
            }
            uint32_t t0 = psm[((size_t)(lane      ) << 11) + (a0 >> 5)];
            uint32_t t1 = psm[((size_t)(lane +  64) << 11) + (a1 >> 5)];
            uint32_t t2 = psm[((size_t)(lane + 128) << 11) + (a2 >> 5)];
            uint32_t t3 = psm[((size_t)(lane + 192) << 11) + (a3 >> 5)];
            sb0 = (t0 >> (a0 & 31)) & 1u;
            sb1 = (t1 >> (a1 & 31)) & 1u;
            sb2 = (t2 >> (a2 & 31)) & 1u;
            sb3 = (t3 >> (a3 & 31)) & 1u;
        }
        u64 q0 = __ballot(sb0 != 0u);
        u64 q1 = __ballot(sb1 != 0u);
        u64 q2 = __ballot(sb2 != 0u);
        u64 q3 = __ballot(sb3 != 0u);
        if (lane < 8) {
            int mi = lane >> 1;
            u64 qq = (mi == 0) ? q0 : (mi == 1) ? q1 : (mi == 2) ? q2 : q3;
            ctx[base + 8 + lane] = (uint32_t)(qq >> ((lane & 1) * 32));
        }
    }

    if (s == 0) {
        final_state[(size_t)gb * N_ST + lane +   0] = (int)sb0;
        final_state[(size_t)gb * N_ST + lane +  64] = (int)sb1;
        final_state[(size_t)gb * N_ST + lane + 128] = (int)sb2;
        final_state[(size_t)gb * N_ST + lane + 192] = (int)sb3;
    }
}

// ---------------- Fallback (ws too small): round-4 kernel, raw tables -------
__global__ __launch_bounds__(1024)
void ram_automaton_fallback(
    const uint32_t* __restrict__ seq_bits, const uint32_t* __restrict__ init_state,
    const int* __restrict__ input_conn, const int* __restrict__ state_conn,
    const uint32_t* __restrict__ im_raw, const uint32_t* __restrict__ sm_raw,
    int* __restrict__ outs, int* __restrict__ final_state)
{
    __shared__ uint32_t c0[16];
    __shared__ uint32_t c1[40];
    const int b = blockIdx.x, tid = threadIdx.x, lane = tid & 63;
    int ic[NB];
#pragma unroll
    for (int k = 0; k < NB; k++) ic[k] = input_conn[tid * NB + k];
    int sc[NB];
    if (tid < N_ST) {
#pragma unroll
        for (int k = 0; k < NB; k++) sc[k] = state_conn[tid * NB + k];
    }
    uint32_t nsbit = 0;
    if (tid < N_ST) nsbit = (init_state[(size_t)b * STATE_BITS + tid] != 0u) ? 1u : 0u;
    uint32_t inbit = 0;
    if (tid < INPUT_BITS) inbit = seq_bits[(size_t)b * INPUT_BITS + tid];
    for (int t = 0; t < SEQ; t++) {
        if (tid < INPUT_BITS) {
            u64 mi = __ballot(inbit != 0u);
            u64 ms = __ballot(nsbit != 0u);
            if ((lane & 31) == 0) {
                c0[tid >> 5] = (uint32_t)(mi >> (lane & 32));
                uint32_t wsd = (uint32_t)(ms >> (lane & 32));
                c0[8 + (tid >> 5)] = wsd; c1[32 + (tid >> 5)] = wsd;
            }
        }
        __syncthreads();
        if (t + 1 < SEQ && tid < INPUT_BITS)
            inbit = seq_bits[((size_t)(t + 1) * BATCH + b) * INPUT_BITS + tid];
        {
            int addr = 0;
#pragma unroll
            for (int k = 0; k < NB; k++) {
                int c = ic[k];
                addr |= (int)((c0[c >> 5] >> (c & 31)) & 1u) << k;
            }
            uint32_t bit = (im_raw[((size_t)tid << 16) + (size_t)addr] != 0u) ? 1u : 0u;
            __builtin_nontemporal_store((int)bit, outs + ((size_t)t * BATCH + b) * N_IN + tid);
            u64 m = __ballot(bit != 0u);
            if (lane == 0) { c1[tid >> 5] = (uint32_t)m; c1[(tid >> 5) + 1] = (uint32_t)(m >> 32); }
        }
        __syncthreads();
        if (tid < N_ST) {
            int addr = 0;
#pragma unroll
            for (int k = 0; k < NB; k++) {
                int c = sc[k];
                addr |= (int)((c1[c >> 5] >> (c & 31)) & 1u) << k;
            }
            nsbit = (sm_raw[((size_t)tid << 16) + (size_t)addr] != 0u) ? 1u : 0u;
        }
        __syncthreads();
    }
    if (tid < N_ST) final_state[(size_t)b * N_ST + tid] = (int)nsbit;
}

extern "C" void kernel_launch(void* const* d_in, const int* in_sizes, int n_in,
                              void* d_out, int out_size, void* d_ws, size_t ws_size,
                              hipStream_t stream) {
    const uint32_t* seq        = (const uint32_t*)d_in[0];
    const uint32_t* init_state = (const uint32_t*)d_in[1];
    const int*      input_conn = (const int*)d_in[2];
    const uint32_t* input_mem  = (const uint32_t*)d_in[3];
    const int*      state_conn = (const int*)d_in[4];
    const uint32_t* state_mem  = (const uint32_t*)d_in[5];

    int* outs = (int*)d_out;                       // [SEQ][BATCH][N_IN]
    int* fin  = outs + (size_t)SEQ * BATCH * N_IN; // [BATCH][N_ST]

    const size_t ex_u64    = (size_t)EX_SLOTS * BATCH * 32; // 32768 u64 = 256 KB
    const size_t pim_words = (size_t)N_IN * RAM_WORDS;      // 2,097,152
    const size_t psm_words = (size_t)N_ST * RAM_WORDS;      //   524,288
    const size_t pseq_words = (size_t)SEQ * BATCH * 8;      //   262,144
    const size_t pinit_words = (size_t)BATCH * 8;           //     2,048
    const size_t need = ex_u64 * 8 +
        (pim_words + psm_words + pseq_words + pinit_words) * 4;

    if (ws_size >= need) {
        u64*      ex    = (u64*)d_ws;
        uint32_t* pim   = (uint32_t*)(ex + ex_u64);
        uint32_t* psm   = pim + pim_words;
        uint32_t* pseq  = psm + psm_words;
        uint32_t* pinit = pseq + pseq_words;

        hipLaunchKernelGGL(pack_bits_kernel, dim3((unsigned)(pim_words / 256)),
                           dim3(256), 0, stream, (const u32x4*)input_mem, pim);
        hipLaunchKernelGGL(pack_bits_kernel, dim3((unsigned)(psm_words / 256)),
                           dim3(256), 0, stream, (const u32x4*)state_mem, psm);
        hipLaunchKernelGGL(pack_bits_kernel, dim3((unsigned)(pseq_words / 256)),
                           dim3(256), 0, stream, (const u32x4*)seq, pseq);
        hipLaunchKernelGGL(pack_bits_kernel, dim3((unsigned)(pinit_words / 256)),
                           dim3(256), 0, stream, (const u32x4*)init_state, pinit);

        hipLaunchKernelGGL(ram_sliced4_kernel, dim3(BATCH), dim3(256), 0, stream,
                           pseq, pinit, input_conn, state_conn, pim, psm,
                           ex, outs, fin);
    } else {
        hipLaunchKernelGGL(ram_automaton_fallback, dim3(BATCH), dim3(1024), 0, stream,
                           seq, init_state, input_conn, state_conn,
                           input_mem, state_mem, outs, fin);
    }
}

// Round 9
// 945.951 us; speedup vs baseline: 1.2233x; 1.2007x over previous
//
#include <hip/hip_runtime.h>
#include <stdint.h>

#define SEQ 128
#define BATCH 256
#define INPUT_BITS 256
#define STATE_BITS 256
#define N_IN 1024
#define N_ST 256
#define NB 16
#define RAM_WORDS 2048   // 2^16 bits / 32 bits per word

typedef unsigned long long u64;
typedef uint32_t u32x4 __attribute__((ext_vector_type(4)));

// Pack "bool as 32-bit word" -> bitmask. One output word per thread from 32
// consecutive source words (8 x vec4 nt loads).
__global__ __launch_bounds__(256)
void pack_bits_kernel(const u32x4* __restrict__ src, uint32_t* __restrict__ dst) {
    int i = blockIdx.x * blockDim.x + threadIdx.x;   // output word index
    const u32x4* p = src + (size_t)i * 8;
    uint32_t w = 0;
#pragma unroll
    for (int j = 0; j < 8; j++) {
        u32x4 v = __builtin_nontemporal_load(p + j);
        w |= (v.x != 0u ? 1u : 0u) << (4 * j + 0);
        w |= (v.y != 0u ? 1u : 0u) << (4 * j + 1);
        w |= (v.z != 0u ? 1u : 0u) << (4 * j + 2);
        w |= (v.w != 0u ? 1u : 0u) << (4 * j + 3);
    }
    dst[i] = w;
}

// Batch-per-block automaton (round-4 structure, the measured optimum:
// fetch-throughput-bound at ~3.7 TB/s of random 64B line fills; exchange-based
// neuron slicing is latency-floored at ~5us/step and loses — rounds 5-8).
//
// Round 9 deltas vs round 4:
//  * double-buffered LDS context (parity = t&1) -> 2 barriers/step, not 3.
//    Safety: A(t+2)'s write to buffer p is ordered behind barrier2(t+1),
//    which is behind barrier1(t+1), which requires every wave's C(t) read
//    of buffer p to have completed.
//  * unified word indexing: input_conn c in [0,512) -> word c>>5 of
//    [input8|state8]; state_conn c in [0,1280) -> word c>>5 of [io32|state8].
__global__ __launch_bounds__(1024)
void ram_automaton_kernel(
    const uint32_t* __restrict__ seq_bits,   // [SEQ][BATCH][INPUT_BITS] bool-as-i32
    const uint32_t* __restrict__ init_state, // [BATCH][STATE_BITS]
    const int*      __restrict__ input_conn, // [N_IN][NB]
    const int*      __restrict__ state_conn, // [N_ST][NB]
    const uint32_t* __restrict__ pim,        // packed input tables [N_IN][2048]
    const uint32_t* __restrict__ psm,        // packed state tables [N_ST][2048]
    int* __restrict__ outs,                  // [SEQ][BATCH][N_IN]
    int* __restrict__ final_state)           // [BATCH][N_ST]
{
    __shared__ uint32_t c0[2][16];  // [input bits (8 words) | state (8 words)]
    __shared__ uint32_t c1[2][40];  // [io bits (32 words)   | state (8 words)]

    const int b = blockIdx.x;
    const int tid = threadIdx.x;
    const int lane = tid & 63;

    // Connection tables in registers (reused for all 128 steps).
    int ic[NB];
#pragma unroll
    for (int k = 0; k < NB; k++) ic[k] = input_conn[tid * NB + k];
    int sc[NB];
    if (tid < N_ST) {
#pragma unroll
        for (int k = 0; k < NB; k++) sc[k] = state_conn[tid * NB + k];
    }

    // Recurrent state bit in a register (tid<256 owns state bit tid).
    uint32_t nsbit = 0;
    if (tid < N_ST) nsbit = (init_state[(size_t)b * STATE_BITS + tid] != 0u) ? 1u : 0u;

    // Prefetched input bit for step t (tid<256 owns input bit tid).
    uint32_t inbit = 0;
    if (tid < INPUT_BITS) inbit = seq_bits[(size_t)b * INPUT_BITS + tid];

    for (int t = 0; t < SEQ; t++) {
        const int p = t & 1;
        uint32_t* c0p = c0[p];
        uint32_t* c1p = c1[p];

        // Phase A: commit this step's input bits + current state into buffer p.
        if (tid < INPUT_BITS) {
            u64 mi = __ballot(inbit != 0u);
            u64 ms = __ballot(nsbit != 0u);
            if ((lane & 31) == 0) {
                c0p[tid >> 5] = (uint32_t)(mi >> (lane & 32));
                uint32_t wsd = (uint32_t)(ms >> (lane & 32));
                c0p[8 + (tid >> 5)]  = wsd;
                c1p[32 + (tid >> 5)] = wsd;
            }
        }
        __syncthreads();   // barrier 1

        // Prefetch next step's input bit (streamed once; off critical path).
        if (t + 1 < SEQ && tid < INPUT_BITS)
            inbit = __builtin_nontemporal_load(
                seq_bits + ((size_t)(t + 1) * BATCH + b) * INPUT_BITS + tid);

        // Phase B: input layer, neuron = tid.
        {
            int addr = 0;
#pragma unroll
            for (int k = 0; k < NB; k++) {
                int c = ic[k];
                addr |= (int)((c0p[c >> 5] >> (c & 31)) & 1u) << k;
            }
            uint32_t w = pim[((size_t)tid << 11) + (addr >> 5)];
            uint32_t bit = (w >> (addr & 31)) & 1u;
            __builtin_nontemporal_store((int)bit,
                outs + ((size_t)t * BATCH + b) * N_IN + tid);
            u64 m = __ballot(bit != 0u);
            if (lane == 0) {
                c1p[(tid >> 5)]     = (uint32_t)m;
                c1p[(tid >> 5) + 1] = (uint32_t)(m >> 32);
            }
        }
        __syncthreads();   // barrier 2

        // Phase C: state layer -> register (committed at next step's phase A
        // into the OTHER buffer; no third barrier needed).
        if (tid < N_ST) {
            int addr = 0;
#pragma unroll
            for (int k = 0; k < NB; k++) {
                int c = sc[k];
                addr |= (int)((c1p[c >> 5] >> (c & 31)) & 1u) << k;
            }
            uint32_t w = psm[((size_t)tid << 11) + (addr >> 5)];
            nsbit = (w >> (addr & 31)) & 1u;
        }
    }

    if (tid < N_ST) final_state[(size_t)b * N_ST + tid] = (int)nsbit;
}

// ---------------- Fallback (ws too small): raw tables, 3-barrier ------------
__global__ __launch_bounds__(1024)
void ram_automaton_fallback(
    const uint32_t* __restrict__ seq_bits, const uint32_t* __restrict__ init_state,
    const int* __restrict__ input_conn, const int* __restrict__ state_conn,
    const uint32_t* __restrict__ im_raw, const uint32_t* __restrict__ sm_raw,
    int* __restrict__ outs, int* __restrict__ final_state)
{
    __shared__ uint32_t c0[16];
    __shared__ uint32_t c1[40];
    const int b = blockIdx.x, tid = threadIdx.x, lane = tid & 63;
    int ic[NB];
#pragma unroll
    for (int k = 0; k < NB; k++) ic[k] = input_conn[tid * NB + k];
    int sc[NB];
    if (tid < N_ST) {
#pragma unroll
        for (int k = 0; k < NB; k++) sc[k] = state_conn[tid * NB + k];
    }
    uint32_t nsbit = 0;
    if (tid < N_ST) nsbit = (init_state[(size_t)b * STATE_BITS + tid] != 0u) ? 1u : 0u;
    uint32_t inbit = 0;
    if (tid < INPUT_BITS) inbit = seq_bits[(size_t)b * INPUT_BITS + tid];
    for (int t = 0; t < SEQ; t++) {
        if (tid < INPUT_BITS) {
            u64 mi = __ballot(inbit != 0u);
            u64 ms = __ballot(nsbit != 0u);
            if ((lane & 31) == 0) {
                c0[tid >> 5] = (uint32_t)(mi >> (lane & 32));
                uint32_t wsd = (uint32_t)(ms >> (lane & 32));
                c0[8 + (tid >> 5)] = wsd; c1[32 + (tid >> 5)] = wsd;
            }
        }
        __syncthreads();
        if (t + 1 < SEQ && tid < INPUT_BITS)
            inbit = seq_bits[((size_t)(t + 1) * BATCH + b) * INPUT_BITS + tid];
        {
            int addr = 0;
#pragma unroll
            for (int k = 0; k < NB; k++) {
                int c = ic[k];
                addr |= (int)((c0[c >> 5] >> (c & 31)) & 1u) << k;
            }
            uint32_t bit = (im_raw[((size_t)tid << 16) + (size_t)addr] != 0u) ? 1u : 0u;
            __builtin_nontemporal_store((int)bit, outs + ((size_t)t * BATCH + b) * N_IN + tid);
            u64 m = __ballot(bit != 0u);
            if (lane == 0) { c1[tid >> 5] = (uint32_t)m; c1[(tid >> 5) + 1] = (uint32_t)(m >> 32); }
        }
        __syncthreads();
        if (tid < N_ST) {
            int addr = 0;
#pragma unroll
            for (int k = 0; k < NB; k++) {
                int c = sc[k];
                addr |= (int)((c1[c >> 5] >> (c & 31)) & 1u) << k;
            }
            nsbit = (sm_raw[((size_t)tid << 16) + (size_t)addr] != 0u) ? 1u : 0u;
        }
        __syncthreads();
    }
    if (tid < N_ST) final_state[(size_t)b * N_ST + tid] = (int)nsbit;
}

extern "C" void kernel_launch(void* const* d_in, const int* in_sizes, int n_in,
                              void* d_out, int out_size, void* d_ws, size_t ws_size,
                              hipStream_t stream) {
    const uint32_t* seq        = (const uint32_t*)d_in[0]; // input_seq_bits
    const uint32_t* init_state = (const uint32_t*)d_in[1]; // init_state
    const int*      input_conn = (const int*)d_in[2];      // input_conn
    const uint32_t* input_mem  = (const uint32_t*)d_in[3]; // input_mem
    const int*      state_conn = (const int*)d_in[4];      // state_conn
    const uint32_t* state_mem  = (const uint32_t*)d_in[5]; // state_mem

    int* outs = (int*)d_out;                       // [SEQ][BATCH][N_IN]
    int* fin  = outs + (size_t)SEQ * BATCH * N_IN; // [BATCH][N_ST]

    const size_t pim_words = (size_t)N_IN * RAM_WORDS;  // 2,097,152 (8 MB)
    const size_t psm_words = (size_t)N_ST * RAM_WORDS;  //   524,288 (2 MB)
    const size_t need = (pim_words + psm_words) * sizeof(uint32_t);

    if (ws_size >= need) {
        uint32_t* pim = (uint32_t*)d_ws;
        uint32_t* psm = pim + pim_words;
        hipLaunchKernelGGL(pack_bits_kernel, dim3((unsigned)(pim_words / 256)),
                           dim3(256), 0, stream, (const u32x4*)input_mem, pim);
        hipLaunchKernelGGL(pack_bits_kernel, dim3((unsigned)(psm_words / 256)),
                           dim3(256), 0, stream, (const u32x4*)state_mem, psm);
        hipLaunchKernelGGL(ram_automaton_kernel, dim3(BATCH), dim3(1024), 0, stream,
                           seq, init_state, input_conn, state_conn,
                           pim, psm, outs, fin);
    } else {
        hipLaunchKernelGGL(ram_automaton_fallback, dim3(BATCH), dim3(1024), 0, stream,
                           seq, init_state, input_conn, state_conn,
                           input_mem, state_mem, outs, fin);
    }
}